// Round 7
// baseline (370.540 us; speedup 1.0000x reference)
//
#include <hip/hip_runtime.h>

// Problem: out = u2 + trilinear(u1, grid + u2); B=2, D=H=W=160, C=3, fp32.
constexpr int Bn = 2;
constexpr int Dn = 160;
constexpr int Hn = 160;
constexpr int Wn = 160;
constexpr int NV  = Bn * Dn * Hn * Wn;         // 8,192,000 voxels
constexpr int VOL = Dn * Hn * Wn;              // 4,096,000 voxels / batch

constexpr int TPB  = 256;
constexpr int NBLK = NV / TPB;                 // 32000 blocks (exact)
constexpr int NXCD = 8;
constexpr int CHUNK = NBLK / NXCD;             // 4000 blocks per XCD chunk

__global__ __launch_bounds__(TPB) void compose_transform_kernel(
    const float* __restrict__ warp1,
    const float* __restrict__ warp2,
    float* __restrict__ out) {

    // XCD-chunked swizzle (proven: FETCH 389->100 MB). Bijective since
    // NBLK % NXCD == 0.
    int bid = blockIdx.x;
    int swz = (bid & (NXCD - 1)) * CHUNK + (bid >> 3);

    int idx = swz * TPB + (int)threadIdx.x;    // voxel id over B*D*H*W

    // decode (b, d, h, w)
    int w  = idx % Wn;
    int t  = idx / Wn;
    int h  = t % Hn;
    t      = t / Hn;
    int d  = t % Dn;
    int b  = t / Dn;

    int base3 = idx * 3;
    // streaming read — nontemporal to keep L2/L3 for the warp1 gathers
    float u2x = __builtin_nontemporal_load(warp2 + base3 + 0);
    float u2y = __builtin_nontemporal_load(warp2 + base3 + 1);
    float u2z = __builtin_nontemporal_load(warp2 + base3 + 2);

    // loc = grid + u2, clipped to [0, size-1]
    float lx = fminf(fmaxf((float)d + u2x, 0.0f), (float)(Dn - 1));
    float ly = fminf(fmaxf((float)h + u2y, 0.0f), (float)(Hn - 1));
    float lz = fminf(fmaxf((float)w + u2z, 0.0f), (float)(Wn - 1));

    // Border-remapped bases: ixb in [0, size-2]; the clamped duplicate corner
    // gets full weight — matches i1=min(i0+1,..) reference semantics exactly.
    int ixb = min((int)floorf(lx), Dn - 2);
    int iyb = min((int)floorf(ly), Hn - 2);
    int izb = min((int)floorf(lz), Wn - 2);

    float wx1 = lx - (float)ixb, wx0 = 1.0f - wx1;
    float wy1 = ly - (float)iyb, wy0 = 1.0f - wy1;
    float wz1 = lz - (float)izb, wz0 = 1.0f - wz1;

    const float* __restrict__ u1 = warp1 + b * (VOL * 3);

    // 4 (x,y) rows; each row reads voxels (izb, izb+1) = 6 contiguous floats.
    const float* p00 = u1 + ((ixb * Hn + iyb) * Wn + izb) * 3;
    const float* p01 = p00 + Wn * 3;           // iyb+1
    const float* p10 = p00 + Hn * Wn * 3;      // ixb+1
    const float* p11 = p10 + Wn * 3;           // ixb+1, iyb+1

    // Issue all 24 gather loads, then force ALL results live across one asm
    // fence ("+v" operands). This compels the scheduler to issue the loads as
    // a single burst with 24 outstanding (MLP=24) instead of its default
    // 4-6-deep load/use interleave (VGPR_Count=24 in R3/R5/R6 proves it was
    // batching). A bare "memory" clobber is NOT enough — register-only FMAs
    // could still be interleaved above it.
    float a00_0 = p00[0], a00_1 = p00[1], a00_2 = p00[2];
    float a00_3 = p00[3], a00_4 = p00[4], a00_5 = p00[5];
    float a01_0 = p01[0], a01_1 = p01[1], a01_2 = p01[2];
    float a01_3 = p01[3], a01_4 = p01[4], a01_5 = p01[5];
    float a10_0 = p10[0], a10_1 = p10[1], a10_2 = p10[2];
    float a10_3 = p10[3], a10_4 = p10[4], a10_5 = p10[5];
    float a11_0 = p11[0], a11_1 = p11[1], a11_2 = p11[2];
    float a11_3 = p11[3], a11_4 = p11[4], a11_5 = p11[5];

    asm volatile(""
        : "+v"(a00_0), "+v"(a00_1), "+v"(a00_2), "+v"(a00_3), "+v"(a00_4), "+v"(a00_5),
          "+v"(a01_0), "+v"(a01_1), "+v"(a01_2), "+v"(a01_3), "+v"(a01_4), "+v"(a01_5),
          "+v"(a10_0), "+v"(a10_1), "+v"(a10_2), "+v"(a10_3), "+v"(a10_4), "+v"(a10_5),
          "+v"(a11_0), "+v"(a11_1), "+v"(a11_2), "+v"(a11_3), "+v"(a11_4), "+v"(a11_5));

    float w00 = wx0 * wy0;
    float w01 = wx0 * wy1;
    float w10 = wx1 * wy0;
    float w11 = wx1 * wy1;

    // Per row: wz0 * c[z0] + wz1 * c[z1], then weighted by wxy.
    float rx, ry, rz;
    float accx, accy, accz;

    rx = fmaf(wz1, a00_3, wz0 * a00_0);
    ry = fmaf(wz1, a00_4, wz0 * a00_1);
    rz = fmaf(wz1, a00_5, wz0 * a00_2);
    accx = w00 * rx; accy = w00 * ry; accz = w00 * rz;

    rx = fmaf(wz1, a01_3, wz0 * a01_0);
    ry = fmaf(wz1, a01_4, wz0 * a01_1);
    rz = fmaf(wz1, a01_5, wz0 * a01_2);
    accx = fmaf(w01, rx, accx); accy = fmaf(w01, ry, accy); accz = fmaf(w01, rz, accz);

    rx = fmaf(wz1, a10_3, wz0 * a10_0);
    ry = fmaf(wz1, a10_4, wz0 * a10_1);
    rz = fmaf(wz1, a10_5, wz0 * a10_2);
    accx = fmaf(w10, rx, accx); accy = fmaf(w10, ry, accy); accz = fmaf(w10, rz, accz);

    rx = fmaf(wz1, a11_3, wz0 * a11_0);
    ry = fmaf(wz1, a11_4, wz0 * a11_1);
    rz = fmaf(wz1, a11_5, wz0 * a11_2);
    accx = fmaf(w11, rx, accx); accy = fmaf(w11, ry, accy); accz = fmaf(w11, rz, accz);

    // streaming write — scalar nontemporal (WRITE_SIZE exactly 96000 KB)
    __builtin_nontemporal_store(u2x + accx, out + base3 + 0);
    __builtin_nontemporal_store(u2y + accy, out + base3 + 1);
    __builtin_nontemporal_store(u2z + accz, out + base3 + 2);
}

extern "C" void kernel_launch(void* const* d_in, const int* in_sizes, int n_in,
                              void* d_out, int out_size, void* d_ws, size_t ws_size,
                              hipStream_t stream) {
    const float* warp1 = (const float*)d_in[0];
    const float* warp2 = (const float*)d_in[1];
    float* out = (float*)d_out;

    compose_transform_kernel<<<NBLK, TPB, 0, stream>>>(warp1, warp2, out);
}

// Round 8
// 350.025 us; speedup vs baseline: 1.0586x; 1.0586x over previous
//
#include <hip/hip_runtime.h>

// Problem: out = u2 + trilinear(u1, grid + u2); B=2, D=H=W=160, C=3, fp32.
//
// R0-R7 evidence: divergent per-voxel gather is stuck at ~190 us regardless of
// instruction shape (scalar/dwordx2/dwordx4/MLP-fence) or HBM traffic -> the
// per-CU L1/TA pipe is saturated by ~30-line fan-out per wave-gather and L1
// (32KB) thrashes. Fix: stage warp1 tiles in LDS via coalesced
// global_load_lds; serve the 8-corner gather from LDS; rare out-of-halo
// voxels (P ~ 2.5e-5) fall back to the verified global path.
constexpr int Bn = 2, Dn = 160, Hn = 160, Wn = 160;
constexpr int VOL = Dn * Hn * Wn;              // 4,096,000 voxels / batch
constexpr int NV  = Bn * VOL;

constexpr int Td = 8, Th = 8, Tw = 8;          // output tile (512 voxels)
constexpr int TPB = 256;                       // 2 voxels / thread
constexpr int NTd = Dn / Td, NTh = Hn / Th, NTw = Wn / Tw;   // 20 each
constexpr int TILES = Bn * NTd * NTh * NTw;    // 16,000 blocks
constexpr int HALO = 4;
constexpr int SP    = Td + 2 * HALO;           // 16 staged voxels / dim
constexpr int SROW  = SP * 3 + 1;              // 49 dwords per (dd,hh) row (+1 pad)
constexpr int SLICE = SP * SROW;               // 784 dwords per dd-slice
constexpr int SDW   = SP * SLICE;              // 12,544 dwords = 50,176 B LDS
constexpr int NIT   = SDW / TPB;               // 49 staging iters, exact
constexpr int NXCD = 8;
constexpr int CHUNK = TILES / NXCD;            // 2000 (bijective swizzle)

typedef const __attribute__((address_space(1))) unsigned int* gas1_t;
typedef __attribute__((address_space(3))) unsigned int* las3_t;

__global__ __launch_bounds__(TPB) void compose_transform_kernel(
    const float* __restrict__ warp1,
    const float* __restrict__ warp2,
    float* __restrict__ out) {

    __shared__ float lds[SDW];

    // XCD-chunked swizzle (proven: keeps halo re-reads in one XCD's L2).
    int bid = blockIdx.x;
    int swz = (bid & (NXCD - 1)) * CHUNK + (bid >> 3);

    int wt = swz % NTw; int t = swz / NTw;
    int ht = t % NTh;   t /= NTh;
    int dt = t % NTd;   int b = t / NTd;
    int d0 = dt * Td, h0 = ht * Th, w0 = wt * Tw;
    int dB = d0 - HALO, hB = h0 - HALO, wB = w0 - HALO;

    const float* __restrict__ u1 = warp1 + (size_t)b * (VOL * 3);
    int tid = (int)threadIdx.x;

    // ---------------- Phase 1: stage 16^3 warp1 tile into LDS ----------------
    // Flat dword id q = tid + 256*it over [0, SDW). Row r = q/49 -> (dd,hh);
    // k = q%49 -> voxel wv = k/3, component c = k%3. Source coords clamp to
    // the volume (border tiles); pad dword (k==48) loads clamped garbage,
    // never read. Dest LDS dword = q (linear: wave-uniform base + lane*4,
    // exactly global_load_lds's write pattern -> conflict-free).
    {
        int r  = tid / SROW;                   // 0..5
        int k  = tid - r * SROW;               // 0..48
        int dd = r >> 4;                       // r / 16
        int hh = r & 15;                       // r % 16
        int wbase = tid & ~63;                 // wave-uniform lane base
#pragma unroll 7
        for (int it = 0; it < NIT; ++it) {
            int wv = (k * 43) >> 7;            // k/3 (valid for k < 128)
            int c  = k - wv * 3;
            int sd = min(max(dB + dd, 0), Dn - 1);
            int sh = min(max(hB + hh, 0), Hn - 1);
            int sw = min(max(wB + wv, 0), Wn - 1);
            int gdw = ((sd * Hn + sh) * Wn + sw) * 3 + c;
            __builtin_amdgcn_global_load_lds(
                (gas1_t)(const unsigned int*)(u1 + gdw),
                (las3_t)((unsigned int*)lds + (wbase + (it << 8))),
                4, 0, 0);
            // increment flat q by 256 = 5 rows (245) + 11 dwords
            k += 11; hh += 5;
            if (k >= SROW) { k -= SROW; hh += 1; }
            if (hh >= SP)  { hh -= SP;  dd += 1; }
        }
    }

    // ------- Phase 2: per-voxel precompute (overlaps staging drain) ---------
    int   ixbA, iybA, izbA, idxA;  bool inbA;
    float wz0A, wz1A, w00A, w01A, w10A, w11A, u2xA, u2yA, u2zA;
    int   ixbB, iybB, izbB, idxB;  bool inbB;
    float wz0B, wz1B, w00B, w01B, w10B, w11B, u2xB, u2yB, u2zB;

#define PRE(SUF, V)                                                          \
    {                                                                        \
        int v = (V);                                                         \
        int ow = v & 7, oh = (v >> 3) & 7, od = v >> 6;                      \
        int d = d0 + od, h = h0 + oh, w = w0 + ow;                           \
        idx##SUF = ((b * Dn + d) * Hn + h) * Wn + w;                         \
        int base3 = idx##SUF * 3;                                            \
        u2x##SUF = __builtin_nontemporal_load(warp2 + base3 + 0);            \
        u2y##SUF = __builtin_nontemporal_load(warp2 + base3 + 1);            \
        u2z##SUF = __builtin_nontemporal_load(warp2 + base3 + 2);            \
        float lx = fminf(fmaxf((float)d + u2x##SUF, 0.0f), (float)(Dn - 1)); \
        float ly = fminf(fmaxf((float)h + u2y##SUF, 0.0f), (float)(Hn - 1)); \
        float lz = fminf(fmaxf((float)w + u2z##SUF, 0.0f), (float)(Wn - 1)); \
        ixb##SUF = min((int)floorf(lx), Dn - 2);                             \
        iyb##SUF = min((int)floorf(ly), Hn - 2);                             \
        izb##SUF = min((int)floorf(lz), Wn - 2);                             \
        float wx1 = lx - (float)ixb##SUF, wx0 = 1.0f - wx1;                  \
        float wy1 = ly - (float)iyb##SUF, wy0 = 1.0f - wy1;                  \
        wz1##SUF = lz - (float)izb##SUF; wz0##SUF = 1.0f - wz1##SUF;         \
        w00##SUF = wx0 * wy0; w01##SUF = wx0 * wy1;                          \
        w10##SUF = wx1 * wy0; w11##SUF = wx1 * wy1;                          \
        inb##SUF = (ixb##SUF >= dB) & (ixb##SUF <= dB + SP - 2) &            \
                   (iyb##SUF >= hB) & (iyb##SUF <= hB + SP - 2) &            \
                   (izb##SUF >= wB) & (izb##SUF <= wB + SP - 2);             \
    }

    PRE(A, tid)
    PRE(B, tid + TPB)
#undef PRE

    __syncthreads();   // drains staging vmcnt + barrier

    // ---------------- Phase 3: resolve both voxels --------------------------
#define RESOLVE(SUF)                                                         \
    {                                                                        \
        float a00_0, a00_1, a00_2, a00_3, a00_4, a00_5;                      \
        float a01_0, a01_1, a01_2, a01_3, a01_4, a01_5;                      \
        float a10_0, a10_1, a10_2, a10_3, a10_4, a10_5;                      \
        float a11_0, a11_1, a11_2, a11_3, a11_4, a11_5;                      \
        if (__builtin_expect(inb##SUF, 1)) {                                 \
            const float* L = lds + ((ixb##SUF - dB) * SLICE +                \
                                    (iyb##SUF - hB) * SROW +                 \
                                    (izb##SUF - wB) * 3);                    \
            a00_0 = L[0];         a00_1 = L[1];         a00_2 = L[2];        \
            a00_3 = L[3];         a00_4 = L[4];         a00_5 = L[5];        \
            a01_0 = L[SROW+0];    a01_1 = L[SROW+1];    a01_2 = L[SROW+2];   \
            a01_3 = L[SROW+3];    a01_4 = L[SROW+4];    a01_5 = L[SROW+5];   \
            a10_0 = L[SLICE+0];   a10_1 = L[SLICE+1];   a10_2 = L[SLICE+2];  \
            a10_3 = L[SLICE+3];   a10_4 = L[SLICE+4];   a10_5 = L[SLICE+5];  \
            a11_0 = L[SLICE+SROW+0]; a11_1 = L[SLICE+SROW+1];                \
            a11_2 = L[SLICE+SROW+2]; a11_3 = L[SLICE+SROW+3];                \
            a11_4 = L[SLICE+SROW+4]; a11_5 = L[SLICE+SROW+5];                \
        } else {                                                             \
            const float* p00 = u1 + ((ixb##SUF * Hn + iyb##SUF) * Wn +       \
                                     izb##SUF) * 3;                          \
            const float* p01 = p00 + Wn * 3;                                 \
            const float* p10 = p00 + Hn * Wn * 3;                            \
            const float* p11 = p10 + Wn * 3;                                 \
            a00_0 = p00[0]; a00_1 = p00[1]; a00_2 = p00[2];                  \
            a00_3 = p00[3]; a00_4 = p00[4]; a00_5 = p00[5];                  \
            a01_0 = p01[0]; a01_1 = p01[1]; a01_2 = p01[2];                  \
            a01_3 = p01[3]; a01_4 = p01[4]; a01_5 = p01[5];                  \
            a10_0 = p10[0]; a10_1 = p10[1]; a10_2 = p10[2];                  \
            a10_3 = p10[3]; a10_4 = p10[4]; a10_5 = p10[5];                  \
            a11_0 = p11[0]; a11_1 = p11[1]; a11_2 = p11[2];                  \
            a11_3 = p11[3]; a11_4 = p11[4]; a11_5 = p11[5];                  \
        }                                                                    \
        float rx, ry, rz, accx, accy, accz;                                  \
        rx = fmaf(wz1##SUF, a00_3, wz0##SUF * a00_0);                        \
        ry = fmaf(wz1##SUF, a00_4, wz0##SUF * a00_1);                        \
        rz = fmaf(wz1##SUF, a00_5, wz0##SUF * a00_2);                        \
        accx = w00##SUF * rx; accy = w00##SUF * ry; accz = w00##SUF * rz;    \
        rx = fmaf(wz1##SUF, a01_3, wz0##SUF * a01_0);                        \
        ry = fmaf(wz1##SUF, a01_4, wz0##SUF * a01_1);                        \
        rz = fmaf(wz1##SUF, a01_5, wz0##SUF * a01_2);                        \
        accx = fmaf(w01##SUF, rx, accx); accy = fmaf(w01##SUF, ry, accy);    \
        accz = fmaf(w01##SUF, rz, accz);                                     \
        rx = fmaf(wz1##SUF, a10_3, wz0##SUF * a10_0);                        \
        ry = fmaf(wz1##SUF, a10_4, wz0##SUF * a10_1);                        \
        rz = fmaf(wz1##SUF, a10_5, wz0##SUF * a10_2);                        \
        accx = fmaf(w10##SUF, rx, accx); accy = fmaf(w10##SUF, ry, accy);    \
        accz = fmaf(w10##SUF, rz, accz);                                     \
        rx = fmaf(wz1##SUF, a11_3, wz0##SUF * a11_0);                        \
        ry = fmaf(wz1##SUF, a11_4, wz0##SUF * a11_1);                        \
        rz = fmaf(wz1##SUF, a11_5, wz0##SUF * a11_2);                        \
        accx = fmaf(w11##SUF, rx, accx); accy = fmaf(w11##SUF, ry, accy);    \
        accz = fmaf(w11##SUF, rz, accz);                                     \
        int ob = idx##SUF * 3;                                               \
        __builtin_nontemporal_store(u2x##SUF + accx, out + ob + 0);          \
        __builtin_nontemporal_store(u2y##SUF + accy, out + ob + 1);          \
        __builtin_nontemporal_store(u2z##SUF + accz, out + ob + 2);          \
    }

    RESOLVE(A)
    RESOLVE(B)
#undef RESOLVE
}

extern "C" void kernel_launch(void* const* d_in, const int* in_sizes, int n_in,
                              void* d_out, int out_size, void* d_ws, size_t ws_size,
                              hipStream_t stream) {
    const float* warp1 = (const float*)d_in[0];
    const float* warp2 = (const float*)d_in[1];
    float* out = (float*)d_out;

    compose_transform_kernel<<<TILES, TPB, 0, stream>>>(warp1, warp2, out);
}

// Round 9
// 318.476 us; speedup vs baseline: 1.1635x; 1.0991x over previous
//
#include <hip/hip_runtime.h>

// Problem: out = u2 + trilinear(u1, grid + u2); B=2, D=H=W=160, C=3, fp32.
//
// R8 proved the LDS-staged structure (gather off the L1/TA critical path) but
// spent ~1000 VALU instrs/thread on staging address decode (VALUBusy 77.5%).
// R9: SROW=48 (no pad) makes the staging map affine: q = tid + 256*it with
// 256 = 5*48+16, 768 = 16*48  =>  hh = rj (thread-invariant, 3 phases),
// dd = i3 (BLOCK-UNIFORM => SGPR clamps/mul). Staging VALU ~1000 -> ~30.
constexpr int Bn = 2, Dn = 160, Hn = 160, Wn = 160;
constexpr int VOL = Dn * Hn * Wn;              // 4,096,000 voxels / batch
constexpr int NV  = Bn * VOL;

constexpr int Td = 8, Th = 8, Tw = 8;          // output tile (512 voxels)
constexpr int TPB = 256;                       // 2 voxels / thread
constexpr int NTd = Dn / Td, NTh = Hn / Th, NTw = Wn / Tw;   // 20 each
constexpr int TILES = Bn * NTd * NTh * NTw;    // 16,000 blocks
constexpr int HALO = 4;
constexpr int SP    = Td + 2 * HALO;           // 16 staged voxels / dim
constexpr int SROW  = SP * 3;                  // 48 dwords per (dd,hh) row
constexpr int SLICE = SP * SROW;               // 768 dwords per dd-slice
constexpr int SDW   = SP * SLICE;              // 12,288 dwords = 49,152 B LDS
constexpr int DSLICE = Hn * Wn * 3;            // 76,800 dwords per global d-slice
constexpr int NXCD = 8;
constexpr int CHUNK = TILES / NXCD;            // 2000 (bijective swizzle)

typedef const __attribute__((address_space(1))) unsigned int* gas1_t;
typedef __attribute__((address_space(3))) unsigned int* las3_t;

__global__ __launch_bounds__(TPB) void compose_transform_kernel(
    const float* __restrict__ warp1,
    const float* __restrict__ warp2,
    float* __restrict__ out) {

    __shared__ float lds[SDW];

    // XCD-chunked swizzle (proven: keeps halo re-reads in one XCD's L2).
    int bid = blockIdx.x;
    int swz = (bid & (NXCD - 1)) * CHUNK + (bid >> 3);

    int wt = swz % NTw; int t = swz / NTw;
    int ht = t % NTh;   t /= NTh;
    int dt = t % NTd;   int b = t / NTd;
    int d0 = dt * Td, h0 = ht * Th, w0 = wt * Tw;
    int dB = d0 - HALO, hB = h0 - HALO, wB = w0 - HALO;

    const float* __restrict__ u1 = warp1 + (size_t)b * (VOL * 3);
    int tid = (int)threadIdx.x;

    // ---------------- Phase 1: stage 16^3 warp1 tile into LDS ----------------
    // Flat dword q = tid + 256*it, it = 3*i3 + j:
    //   row r = rj + 16*i3  (rj = (tid+256j)/48 in [0,16))  => hh = rj, dd = i3
    //   k = (tid+256j) % 48 (thread-invariant)               => wv, c
    // Per-thread precompute (once): base_j = (sh*Wn + sw)*3 + c with sh,sw
    // clamped. Loop body: sd = clamp(dB+i3) is BLOCK-UNIFORM -> scalar ops.
    // Dest: lane-linear (wave base + lane*4) = flat q -> conflict-free, and
    // matches global_load_lds's fixed write pattern.
    {
        int base0, base1, base2;
#define STAGE_PRE(J, BASE)                                                   \
        {                                                                    \
            int qj = tid + 256 * (J);                                        \
            int rj = qj / SROW;                                              \
            int kj = qj - rj * SROW;                                         \
            int wv = (kj * 43) >> 7;            /* kj/3, kj < 128 */         \
            int c  = kj - wv * 3;                                            \
            int sh = min(max(hB + rj, 0), Hn - 1);                           \
            int sw = min(max(wB + wv, 0), Wn - 1);                           \
            BASE = (sh * Wn + sw) * 3 + c;                                   \
        }
        STAGE_PRE(0, base0)
        STAGE_PRE(1, base1)
        STAGE_PRE(2, base2)
#undef STAGE_PRE

        unsigned wvdst = (unsigned)(tid & ~63);          // wave-uniform
        unsigned int* ldsu = (unsigned int*)lds;
#pragma unroll
        for (int i3 = 0; i3 < SP; ++i3) {
            int sd = min(max(dB + i3, 0), Dn - 1);       // block-uniform
            const unsigned int* slice =
                (const unsigned int*)u1 + (size_t)sd * DSLICE;
            unsigned dstb = wvdst + (unsigned)(i3 * (3 * 256));
            __builtin_amdgcn_global_load_lds((gas1_t)(slice + base0),
                                             (las3_t)(ldsu + dstb), 4, 0, 0);
            __builtin_amdgcn_global_load_lds((gas1_t)(slice + base1),
                                             (las3_t)(ldsu + dstb + 256), 4, 0, 0);
            __builtin_amdgcn_global_load_lds((gas1_t)(slice + base2),
                                             (las3_t)(ldsu + dstb + 512), 4, 0, 0);
        }
    }

    // ------- Phase 2: per-voxel precompute (overlaps staging drain) ---------
    int   ixbA, iybA, izbA, idxA;  bool inbA;
    float wz0A, wz1A, w00A, w01A, w10A, w11A, u2xA, u2yA, u2zA;
    int   ixbB, iybB, izbB, idxB;  bool inbB;
    float wz0B, wz1B, w00B, w01B, w10B, w11B, u2xB, u2yB, u2zB;

#define PRE(SUF, V)                                                          \
    {                                                                        \
        int v = (V);                                                         \
        int ow = v & 7, oh = (v >> 3) & 7, od = v >> 6;                      \
        int d = d0 + od, h = h0 + oh, w = w0 + ow;                           \
        idx##SUF = ((b * Dn + d) * Hn + h) * Wn + w;                         \
        int base3 = idx##SUF * 3;                                            \
        u2x##SUF = __builtin_nontemporal_load(warp2 + base3 + 0);            \
        u2y##SUF = __builtin_nontemporal_load(warp2 + base3 + 1);            \
        u2z##SUF = __builtin_nontemporal_load(warp2 + base3 + 2);            \
        float lx = fminf(fmaxf((float)d + u2x##SUF, 0.0f), (float)(Dn - 1)); \
        float ly = fminf(fmaxf((float)h + u2y##SUF, 0.0f), (float)(Hn - 1)); \
        float lz = fminf(fmaxf((float)w + u2z##SUF, 0.0f), (float)(Wn - 1)); \
        ixb##SUF = min((int)floorf(lx), Dn - 2);                             \
        iyb##SUF = min((int)floorf(ly), Hn - 2);                             \
        izb##SUF = min((int)floorf(lz), Wn - 2);                             \
        float wx1 = lx - (float)ixb##SUF, wx0 = 1.0f - wx1;                  \
        float wy1 = ly - (float)iyb##SUF, wy0 = 1.0f - wy1;                  \
        wz1##SUF = lz - (float)izb##SUF; wz0##SUF = 1.0f - wz1##SUF;         \
        w00##SUF = wx0 * wy0; w01##SUF = wx0 * wy1;                          \
        w10##SUF = wx1 * wy0; w11##SUF = wx1 * wy1;                          \
        inb##SUF = (ixb##SUF >= dB) & (ixb##SUF <= dB + SP - 2) &            \
                   (iyb##SUF >= hB) & (iyb##SUF <= hB + SP - 2) &            \
                   (izb##SUF >= wB) & (izb##SUF <= wB + SP - 2);             \
    }

    PRE(A, tid)
    PRE(B, tid + TPB)
#undef PRE

    __syncthreads();   // drains staging vmcnt + barrier

    // ---------------- Phase 3: resolve both voxels --------------------------
#define RESOLVE(SUF)                                                         \
    {                                                                        \
        float a00_0, a00_1, a00_2, a00_3, a00_4, a00_5;                      \
        float a01_0, a01_1, a01_2, a01_3, a01_4, a01_5;                      \
        float a10_0, a10_1, a10_2, a10_3, a10_4, a10_5;                      \
        float a11_0, a11_1, a11_2, a11_3, a11_4, a11_5;                      \
        if (__builtin_expect(inb##SUF, 1)) {                                 \
            const float* L = lds + ((ixb##SUF - dB) * SLICE +                \
                                    (iyb##SUF - hB) * SROW +                 \
                                    (izb##SUF - wB) * 3);                    \
            a00_0 = L[0];         a00_1 = L[1];         a00_2 = L[2];        \
            a00_3 = L[3];         a00_4 = L[4];         a00_5 = L[5];        \
            a01_0 = L[SROW+0];    a01_1 = L[SROW+1];    a01_2 = L[SROW+2];   \
            a01_3 = L[SROW+3];    a01_4 = L[SROW+4];    a01_5 = L[SROW+5];   \
            a10_0 = L[SLICE+0];   a10_1 = L[SLICE+1];   a10_2 = L[SLICE+2];  \
            a10_3 = L[SLICE+3];   a10_4 = L[SLICE+4];   a10_5 = L[SLICE+5];  \
            a11_0 = L[SLICE+SROW+0]; a11_1 = L[SLICE+SROW+1];                \
            a11_2 = L[SLICE+SROW+2]; a11_3 = L[SLICE+SROW+3];                \
            a11_4 = L[SLICE+SROW+4]; a11_5 = L[SLICE+SROW+5];                \
        } else {                                                             \
            const float* p00 = u1 + ((ixb##SUF * Hn + iyb##SUF) * Wn +       \
                                     izb##SUF) * 3;                          \
            const float* p01 = p00 + Wn * 3;                                 \
            const float* p10 = p00 + Hn * Wn * 3;                            \
            const float* p11 = p10 + Wn * 3;                                 \
            a00_0 = p00[0]; a00_1 = p00[1]; a00_2 = p00[2];                  \
            a00_3 = p00[3]; a00_4 = p00[4]; a00_5 = p00[5];                  \
            a01_0 = p01[0]; a01_1 = p01[1]; a01_2 = p01[2];                  \
            a01_3 = p01[3]; a01_4 = p01[4]; a01_5 = p01[5];                  \
            a10_0 = p10[0]; a10_1 = p10[1]; a10_2 = p10[2];                  \
            a10_3 = p10[3]; a10_4 = p10[4]; a10_5 = p10[5];                  \
            a11_0 = p11[0]; a11_1 = p11[1]; a11_2 = p11[2];                  \
            a11_3 = p11[3]; a11_4 = p11[4]; a11_5 = p11[5];                  \
        }                                                                    \
        float rx, ry, rz, accx, accy, accz;                                  \
        rx = fmaf(wz1##SUF, a00_3, wz0##SUF * a00_0);                        \
        ry = fmaf(wz1##SUF, a00_4, wz0##SUF * a00_1);                        \
        rz = fmaf(wz1##SUF, a00_5, wz0##SUF * a00_2);                        \
        accx = w00##SUF * rx; accy = w00##SUF * ry; accz = w00##SUF * rz;    \
        rx = fmaf(wz1##SUF, a01_3, wz0##SUF * a01_0);                        \
        ry = fmaf(wz1##SUF, a01_4, wz0##SUF * a01_1);                        \
        rz = fmaf(wz1##SUF, a01_5, wz0##SUF * a01_2);                        \
        accx = fmaf(w01##SUF, rx, accx); accy = fmaf(w01##SUF, ry, accy);    \
        accz = fmaf(w01##SUF, rz, accz);                                     \
        rx = fmaf(wz1##SUF, a10_3, wz0##SUF * a10_0);                        \
        ry = fmaf(wz1##SUF, a10_4, wz0##SUF * a10_1);                        \
        rz = fmaf(wz1##SUF, a10_5, wz0##SUF * a10_2);                        \
        accx = fmaf(w10##SUF, rx, accx); accy = fmaf(w10##SUF, ry, accy);    \
        accz = fmaf(w10##SUF, rz, accz);                                     \
        rx = fmaf(wz1##SUF, a11_3, wz0##SUF * a11_0);                        \
        ry = fmaf(wz1##SUF, a11_4, wz0##SUF * a11_1);                        \
        rz = fmaf(wz1##SUF, a11_5, wz0##SUF * a11_2);                        \
        accx = fmaf(w11##SUF, rx, accx); accy = fmaf(w11##SUF, ry, accy);    \
        accz = fmaf(w11##SUF, rz, accz);                                     \
        int ob = idx##SUF * 3;                                               \
        __builtin_nontemporal_store(u2x##SUF + accx, out + ob + 0);          \
        __builtin_nontemporal_store(u2y##SUF + accy, out + ob + 1);          \
        __builtin_nontemporal_store(u2z##SUF + accz, out + ob + 2);          \
    }

    RESOLVE(A)
    RESOLVE(B)
#undef RESOLVE
}

extern "C" void kernel_launch(void* const* d_in, const int* in_sizes, int n_in,
                              void* d_out, int out_size, void* d_ws, size_t ws_size,
                              hipStream_t stream) {
    const float* warp1 = (const float*)d_in[0];
    const float* warp2 = (const float*)d_in[1];
    float* out = (float*)d_out;

    compose_transform_kernel<<<TILES, TPB, 0, stream>>>(warp1, warp2, out);
}